// Round 3
// baseline (136.008 us; speedup 1.0000x reference)
//
#include <hip/hip_runtime.h>

#define KE_KCAL 332.0637f

constexpr int N_ATOMS = 6144;
constexpr int FEAT = 128;
constexpr int NTI = 24;                 // i-tiles of 256 atoms
constexpr int NTJ = 96;                 // j-tiles of 64 atoms
constexpr int NREAL = 1200;             // sum_{bi<24} (96 - 4*bi)
constexpr int NQPART = 64;

// ---------------- kernel A: pred + spread partial sums + pack ---------------
// one 64-lane wave per atom; lane l covers features l and l+64.
// lane 0 writes xqp[i] = {x, y, z, pred} and atomicAdds pred into qpart.
__global__ __launch_bounds__(256) void pred_kernel(
    const float* __restrict__ f, const int* __restrict__ z,
    const float* __restrict__ w, const float* __restrict__ ztab,
    const float* __restrict__ xyz,
    float* __restrict__ qpart, float4* __restrict__ xqp)
{
    int gid  = blockIdx.x * blockDim.x + threadIdx.x;
    int atom = gid >> 6;
    int lane = threadIdx.x & 63;
    if (atom >= N_ATOMS) return;

    const float* frow = f + (size_t)atom * FEAT;
    float p = frow[lane] * w[lane] + frow[lane + 64] * w[lane + 64];
    #pragma unroll
    for (int off = 32; off > 0; off >>= 1)
        p += __shfl_down(p, off, 64);

    if (lane == 0) {
        p += ztab[z[atom]];
        atomicAdd(&qpart[atom & (NQPART - 1)], p);
        xqp[atom] = make_float4(xyz[3*atom], xyz[3*atom+1], xyz[3*atom+2], p);
    }
}

// ---------------- kernel B: pairwise energy, fully fused --------------------
// grid (24, 96): block (bi,bj) handles 256 i-atoms vs 64 j-atoms, bj*64 >=
// bi*256 (others exit before any barrier). corr computed per block from the
// 64 qpart slots (scalar-uniform). j-tile staged in LDS; inner loop does a
// wave-uniform fast path (term = 1/r, exact for r >= 7.5). Diagonal-leading
// blocks (bj == 4*bi) write q to d_out. Last real block finalizes energy.
__global__ __launch_bounds__(256) void pair_kernel(
    const float4* __restrict__ xqp, const float* __restrict__ qpart,
    const float* __restrict__ total_charge,
    float* __restrict__ qout, float* __restrict__ epart,
    unsigned int* __restrict__ counter, float* __restrict__ out0)
{
    int bi = blockIdx.x, bj = blockIdx.y;
    if (bj < 4 * bi) return;            // uniform exit, before barriers
    int t = threadIdx.x;

    // correction term: uniform across all threads -> scalar loads/adds
    float s = 0.f;
    #pragma unroll
    for (int k = 0; k < NQPART; ++k) s += qpart[k];
    float corr = (total_charge[0] - s) * (1.0f / (float)N_ATOMS);

    __shared__ float4 sj[64];
    int gj0 = bj * 64;
    if (t < 64) {
        float4 a = xqp[gj0 + t];
        a.w += corr;                    // q_j
        sj[t] = a;
    }

    int gi = bi * 256 + t;
    float4 pi = xqp[gi];
    float qi = pi.w + corr;
    if (bj == 4 * bi) qout[gi] = qi;    // each i written by exactly one block
    __syncthreads();

    int jthresh = gi - gj0;             // pair valid iff jj > jthresh
    float acc = 0.f;
    #pragma unroll 4
    for (int jj = 0; jj < 64; ++jj) {
        float4 pj = sj[jj];             // broadcast, conflict-free
        float dx = pi.x - pj.x, dy = pi.y - pj.y, dz = pi.z - pj.z;
        float r2 = fmaf(dx, dx, fmaf(dy, dy, dz * dz));
        bool valid = (jj > jthresh) && (r2 > 0.f);
        float r2s = valid ? r2 : 1e8f;  // masked lanes ride the fast path
        float qq  = valid ? qi * pj.w : 0.f;
        float t2  = __builtin_amdgcn_rsqf(r2s);          // 1/r
        float term;
        if (__any(r2s < 56.25f)) {      // any lane inside switch region?
            float r   = r2s * t2;
            float arg = fmaf(r, 0.2f, -0.5f);            // (r-2.5)/5
            float ra  = __builtin_amdgcn_rcpf(fmaxf(arg, 1e-20f));
            float ro  = __builtin_amdgcn_rcpf(fmaxf(1.f - arg, 1e-20f));
            float e   = __expf(ro - ra);                 // saturates to 0/inf
            float fs  = __builtin_amdgcn_rcpf(1.f + e);  // exact 0/1 outside
            float t1  = __builtin_amdgcn_rsqf(r2s + 1.f);
            term = fmaf(fs, t1 - t2, t2);
        } else {
            term = t2;                  // exact: fs == 0 for r >= 7.5
        }
        acc = fmaf(qq, term, acc);
    }

    // block reduction
    #pragma unroll
    for (int off = 32; off > 0; off >>= 1)
        acc += __shfl_down(acc, off, 64);
    __shared__ float wacc[4];
    if ((t & 63) == 0) wacc[t >> 6] = acc;
    __syncthreads();
    if (t == 0) {
        float be = wacc[0] + wacc[1] + wacc[2] + wacc[3];
        atomicAdd(&epart[bj & 63], be);
    }

    // last-real-block energy finalize (wave 0 only)
    if (t < 64) {
        unsigned int old = 0;
        if (t == 0) {
            __threadfence();            // epart add visible before counter
            old = atomicAdd(counter, 1u);
        }
        old = __shfl(old, 0, 64);
        if (old == NREAL - 1) {
            float e = atomicAdd(&epart[t], 0.0f);   // coherent read
            #pragma unroll
            for (int off = 32; off > 0; off >>= 1)
                e += __shfl_down(e, off, 64);
            if (t == 0) out0[0] = KE_KCAL * e;
        }
    }
}

extern "C" void kernel_launch(void* const* d_in, const int* in_sizes, int n_in,
                              void* d_out, int out_size, void* d_ws, size_t ws_size,
                              hipStream_t stream) {
    const float* f    = (const float*)d_in[0];
    const int*   z    = (const int*)  d_in[1];
    const float* xyz  = (const float*)d_in[2];
    const float* qtot = (const float*)d_in[3];
    const float* w    = (const float*)d_in[4];
    const float* ztab = (const float*)d_in[5];
    float* out = (float*)d_out;            // out[0] = energy, out[1..N] = q

    // ws layout: [0,256) qpart[64] | [256,512) epart[64] | [512] counter
    //            [1024, 1024+98304) xqp[N] float4
    char* wsb = (char*)d_ws;
    float*        qpart   = (float*)(wsb + 0);
    float*        epart   = (float*)(wsb + 256);
    unsigned int* counter = (unsigned int*)(wsb + 512);
    float4*       xqp     = (float4*)(wsb + 1024);

    hipMemsetAsync(d_ws, 0, 1024, stream);

    pred_kernel<<<(N_ATOMS * 64) / 256, 256, 0, stream>>>(f, z, w, ztab, xyz,
                                                          qpart, xqp);
    dim3 grid(NTI, NTJ);
    pair_kernel<<<grid, 256, 0, stream>>>(xqp, qpart, qtot, out + 1, epart,
                                          counter, out);
}

// Round 4
// 99.509 us; speedup vs baseline: 1.3668x; 1.3668x over previous
//
#include <hip/hip_runtime.h>

#define KE_KCAL 332.0637f

constexpr int N_ATOMS = 6144;
constexpr int NTI = 12;                 // i-tiles of 512 atoms
constexpr int NTJ = 96;                 // j-tiles of 64 atoms
constexpr int NREAL = 624;              // sum_{bi<12} (96 - 8*bi)
constexpr int NQPART = 64;              // partial-sum slots
constexpr int QSTRIDE = 32;             // floats between slots = 128 B line

// ---------------- kernel A: pred + spread partial sums + pack ---------------
// 4 waves/block, 4 atoms/wave (independent dot-product chains for ILP).
// lane l reads features 2l, 2l+1 as float2. Butterfly reduce leaves the sum
// in all lanes; lanes 0..3 do the per-atom epilogue in parallel. One atomic
// per wave into a line-padded slot (no same-line serialization).
__global__ __launch_bounds__(256) void pred_kernel(
    const float* __restrict__ f, const int* __restrict__ z,
    const float* __restrict__ w, const float* __restrict__ ztab,
    const float* __restrict__ xyz,
    float* __restrict__ qpart, float4* __restrict__ xqp)
{
    int wid  = (blockIdx.x * blockDim.x + threadIdx.x) >> 6;  // global wave id
    int lane = threadIdx.x & 63;
    int base = wid * 4;                  // 4 atoms per wave
    if (base >= N_ATOMS) return;

    const float2* f2 = (const float2*)f;
    float2 wv = ((const float2*)w)[lane];

    float2 v0 = f2[(size_t)(base + 0) * 64 + lane];
    float2 v1 = f2[(size_t)(base + 1) * 64 + lane];
    float2 v2 = f2[(size_t)(base + 2) * 64 + lane];
    float2 v3 = f2[(size_t)(base + 3) * 64 + lane];

    float p0 = fmaf(v0.x, wv.x, v0.y * wv.y);
    float p1 = fmaf(v1.x, wv.x, v1.y * wv.y);
    float p2 = fmaf(v2.x, wv.x, v2.y * wv.y);
    float p3 = fmaf(v3.x, wv.x, v3.y * wv.y);

    #pragma unroll
    for (int off = 32; off > 0; off >>= 1) {
        p0 += __shfl_xor(p0, off, 64);
        p1 += __shfl_xor(p1, off, 64);
        p2 += __shfl_xor(p2, off, 64);
        p3 += __shfl_xor(p3, off, 64);
    }

    float ws_sum = 0.f;
    if (lane < 4) {
        int atom = base + lane;
        float pk = p0;
        pk = (lane == 1) ? p1 : pk;
        pk = (lane == 2) ? p2 : pk;
        pk = (lane == 3) ? p3 : pk;
        pk += ztab[z[atom]];
        xqp[atom] = make_float4(xyz[3*atom], xyz[3*atom+1], xyz[3*atom+2], pk);
        ws_sum = pk;
    }
    // sum lanes 0..3 (xor within the quad)
    ws_sum += __shfl_xor(ws_sum, 1, 64);
    ws_sum += __shfl_xor(ws_sum, 2, 64);
    if (lane == 0)
        atomicAdd(&qpart[(wid & (NQPART - 1)) * QSTRIDE], ws_sum);
}

// ---------------- kernel B: pairwise energy, fused finalize -----------------
// grid (12, 96): block (bi,bj) = 512 i-atoms x 64 j-atoms, only bj >= 8*bi
// survives (uniform exit before barriers). Branchless inner loop, 2 i-atoms
// per lane. fs = 1/(1+exp((2u-1)/(u-u^2))), u clamped -> exact 0/1 saturation.
// Blocks with bj == 8*bi write q to d_out. Last-finishing block finalizes E.
__global__ __launch_bounds__(256) void pair_kernel(
    const float4* __restrict__ xqp, const float* __restrict__ qpart,
    const float* __restrict__ total_charge,
    float* __restrict__ qout, float* __restrict__ epart,
    unsigned int* __restrict__ counter, float* __restrict__ out0)
{
    int bi = blockIdx.x, bj = blockIdx.y;
    if (bj < 8 * bi) return;
    int t = threadIdx.x;

    // charge correction (uniform)
    float s = 0.f;
    #pragma unroll
    for (int k = 0; k < NQPART; ++k) s += qpart[k * QSTRIDE];
    float corr = (total_charge[0] - s) * (1.0f / (float)N_ATOMS);

    __shared__ float4 sj[64];
    int gj0 = bj * 64;
    if (t < 64) {
        float4 a = xqp[gj0 + t];
        a.w += corr;
        sj[t] = a;
    }

    int i0 = bi * 512 + t, i1 = i0 + 256;
    float4 pi0 = xqp[i0], pi1 = xqp[i1];
    float q0 = pi0.w + corr, q1 = pi1.w + corr;
    if (bj == 8 * bi) { qout[i0] = q0; qout[i1] = q1; }
    __syncthreads();

    int jt0 = i0 - gj0, jt1 = i1 - gj0;  // pair valid iff jj > jt
    float acc0 = 0.f, acc1 = 0.f;
    #pragma unroll 8
    for (int jj = 0; jj < 64; ++jj) {
        float4 pj = sj[jj];
        float dx0 = pi0.x - pj.x, dy0 = pi0.y - pj.y, dz0 = pi0.z - pj.z;
        float dx1 = pi1.x - pj.x, dy1 = pi1.y - pj.y, dz1 = pi1.z - pj.z;
        float r20 = fmaf(dx0, dx0, fmaf(dy0, dy0, dz0 * dz0));
        float r21 = fmaf(dx1, dx1, fmaf(dy1, dy1, dz1 * dz1));
        bool m0 = (jj > jt0) && (r20 > 0.f);
        bool m1 = (jj > jt1) && (r21 > 0.f);
        float r2s0 = m0 ? r20 : 1e8f;
        float r2s1 = m1 ? r21 : 1e8f;
        float qq0 = m0 ? q0 * pj.w : 0.f;
        float qq1 = m1 ? q1 * pj.w : 0.f;

        float t20 = __builtin_amdgcn_rsqf(r2s0);          // 1/r
        float t21 = __builtin_amdgcn_rsqf(r2s1);
        float u0 = fmaf(r2s0 * t20, 0.2f, -0.5f);         // (r-2.5)/5
        float u1 = fmaf(r2s1 * t21, 0.2f, -0.5f);
        u0 = fminf(fmaxf(u0, 1e-3f), 0.999f);             // saturates fs to 1/0
        u1 = fminf(fmaxf(u1, 1e-3f), 0.999f);
        float d0 = (u0 + u0 - 1.f) * __builtin_amdgcn_rcpf(fmaf(-u0, u0, u0));
        float d1 = (u1 + u1 - 1.f) * __builtin_amdgcn_rcpf(fmaf(-u1, u1, u1));
        float fs0 = __builtin_amdgcn_rcpf(1.f + __expf(d0));
        float fs1 = __builtin_amdgcn_rcpf(1.f + __expf(d1));
        float t10 = __builtin_amdgcn_rsqf(r2s0 + 1.f);    // 1/sqrt(r2+1)
        float t11 = __builtin_amdgcn_rsqf(r2s1 + 1.f);
        acc0 = fmaf(qq0, fmaf(fs0, t10 - t20, t20), acc0);
        acc1 = fmaf(qq1, fmaf(fs1, t11 - t21, t21), acc1);
    }
    float acc = acc0 + acc1;

    #pragma unroll
    for (int off = 32; off > 0; off >>= 1)
        acc += __shfl_down(acc, off, 64);
    __shared__ float wacc[4];
    if ((t & 63) == 0) wacc[t >> 6] = acc;
    __syncthreads();
    if (t == 0) {
        float be = wacc[0] + wacc[1] + wacc[2] + wacc[3];
        atomicAdd(&epart[((bi * 96 + bj) & 63)], be);
    }

    // last-real-block energy finalize (wave 0)
    if (t < 64) {
        unsigned int old = 0;
        if (t == 0) {
            __threadfence();
            old = atomicAdd(counter, 1u);
        }
        old = __shfl(old, 0, 64);
        if (old == NREAL - 1) {
            float e = atomicAdd(&epart[t], 0.0f);   // coherent read
            #pragma unroll
            for (int off = 32; off > 0; off >>= 1)
                e += __shfl_down(e, off, 64);
            if (t == 0) out0[0] = KE_KCAL * e;
        }
    }
}

extern "C" void kernel_launch(void* const* d_in, const int* in_sizes, int n_in,
                              void* d_out, int out_size, void* d_ws, size_t ws_size,
                              hipStream_t stream) {
    const float* f    = (const float*)d_in[0];
    const int*   z    = (const int*)  d_in[1];
    const float* xyz  = (const float*)d_in[2];
    const float* qtot = (const float*)d_in[3];
    const float* w    = (const float*)d_in[4];
    const float* ztab = (const float*)d_in[5];
    float* out = (float*)d_out;            // out[0] = energy, out[1..N] = q

    // ws: [0,256) epart[64] | [256] counter | [512, 512+8192) qpart padded
    //     [16384, +98304) xqp[N] float4
    char* wsb = (char*)d_ws;
    float*        epart   = (float*)(wsb + 0);
    unsigned int* counter = (unsigned int*)(wsb + 256);
    float*        qpart   = (float*)(wsb + 512);
    float4*       xqp     = (float4*)(wsb + 16384);

    hipMemsetAsync(d_ws, 0, 16384, stream);

    pred_kernel<<<N_ATOMS / 16, 256, 0, stream>>>(f, z, w, ztab, xyz,
                                                  qpart, xqp);
    dim3 grid(NTI, NTJ);
    pair_kernel<<<grid, 256, 0, stream>>>(xqp, qpart, qtot, out + 1, epart,
                                          counter, out);
}

// Round 6
// 94.394 us; speedup vs baseline: 1.4409x; 1.0542x over previous
//
#include <hip/hip_runtime.h>

#define KE_KCAL 332.0637f

constexpr int N_ATOMS = 6144;
constexpr int NTI = 24;                 // i-tiles of 256 atoms
constexpr int NREAL = 1200;             // sum_{bi<24} (96 - 4*bi)
constexpr int NPRED = 384;              // pred blocks (16 atoms each)

// ---------------- kernel A: pred + per-block sums + pack + zero scratch -----
// 384 blocks x 256 threads, 4 atoms/wave. Block b writes qpart[b] (plain
// store). Block 0 additionally zeroes epart[64] + counter (visible to the
// pair kernel via stream-ordered dispatch).
__global__ __launch_bounds__(256) void pred_kernel(
    const float* __restrict__ f, const int* __restrict__ z,
    const float* __restrict__ w, const float* __restrict__ ztab,
    const float* __restrict__ xyz,
    float* __restrict__ qpart, float4* __restrict__ xqp,
    float* __restrict__ epart, unsigned int* __restrict__ counter)
{
    int t = threadIdx.x, b = blockIdx.x;
    int lane = t & 63, wid = t >> 6;

    if (b == 0) {
        if (t < 64) epart[t] = 0.f;
        if (t == 64) *counter = 0u;
    }

    int base = b * 16 + wid * 4;
    const float2* f2 = (const float2*)f;
    float2 wv = ((const float2*)w)[lane];
    float2 v0 = f2[(size_t)(base + 0) * 64 + lane];
    float2 v1 = f2[(size_t)(base + 1) * 64 + lane];
    float2 v2 = f2[(size_t)(base + 2) * 64 + lane];
    float2 v3 = f2[(size_t)(base + 3) * 64 + lane];
    float p0 = fmaf(v0.x, wv.x, v0.y * wv.y);
    float p1 = fmaf(v1.x, wv.x, v1.y * wv.y);
    float p2 = fmaf(v2.x, wv.x, v2.y * wv.y);
    float p3 = fmaf(v3.x, wv.x, v3.y * wv.y);
    #pragma unroll
    for (int off = 32; off > 0; off >>= 1) {
        p0 += __shfl_xor(p0, off, 64);
        p1 += __shfl_xor(p1, off, 64);
        p2 += __shfl_xor(p2, off, 64);
        p3 += __shfl_xor(p3, off, 64);
    }
    float ws_sum = 0.f;
    if (lane < 4) {
        int atom = base + lane;
        float pk = p0;
        pk = (lane == 1) ? p1 : pk;
        pk = (lane == 2) ? p2 : pk;
        pk = (lane == 3) ? p3 : pk;
        pk += ztab[z[atom]];
        xqp[atom] = make_float4(xyz[3*atom], xyz[3*atom+1], xyz[3*atom+2], pk);
        ws_sum = pk;
    }
    ws_sum += __shfl_xor(ws_sum, 1, 64);
    ws_sum += __shfl_xor(ws_sum, 2, 64);

    __shared__ float lred[4];
    if (lane == 0) lred[wid] = ws_sum;
    __syncthreads();
    if (t == 0) qpart[b] = lred[0] + lred[1] + lred[2] + lred[3];
}

// ---------------- kernel B: pairwise energy, fused finalize -----------------
// 1200 triangular blocks x 256 threads (~4.7 blocks/CU, all co-resident).
// Block b -> (bi, bj), bj in [4*bi, 96): 256 i-atoms x 64 j-atoms, 1 i/lane.
// Branchless switch: fs = 1/(1+exp((2u-1)/(u-u^2))), clamped u saturates
// exactly to 0/1. Diagonal blocks (bj==4*bi) write q. Last block finalizes E.
__global__ __launch_bounds__(256) void pair_kernel(
    const float4* __restrict__ xqp, const float* __restrict__ qpart,
    const float* __restrict__ total_charge,
    float* __restrict__ qout, float* __restrict__ epart,
    unsigned int* __restrict__ counter, float* __restrict__ out0)
{
    int t = threadIdx.x, b = blockIdx.x;
    int lane = t & 63, wid = t >> 6;
    __shared__ float lred[4];
    __shared__ float4 sj[64];

    // charge correction from the 384 per-block partials
    float s = qpart[t];
    if (t < NPRED - 256) s += qpart[256 + t];
    #pragma unroll
    for (int off = 32; off > 0; off >>= 1)
        s += __shfl_xor(s, off, 64);
    if (lane == 0) lred[wid] = s;
    __syncthreads();
    float S = lred[0] + lred[1] + lred[2] + lred[3];
    float corr = (total_charge[0] - S) * (1.0f / (float)N_ATOMS);

    // decode triangular (bi, bj)
    int bi = 0, off = 0;
    while (b >= off + (96 - 4 * bi)) { off += 96 - 4 * bi; ++bi; }
    int bj = 4 * bi + (b - off);

    int gj0 = bj * 64;
    if (t < 64) {
        float4 a = xqp[gj0 + t];
        a.w += corr;
        sj[t] = a;
    }
    int gi = bi * 256 + t;
    float4 pi = xqp[gi];
    float qi = pi.w + corr;
    if (bj == 4 * bi) qout[gi] = qi;
    __syncthreads();

    int jthresh = gi - gj0;                   // pair valid iff jj > jthresh
    float acc = 0.f;
    #pragma unroll 8
    for (int jj = 0; jj < 64; ++jj) {
        float4 pj = sj[jj];
        float dx = pi.x - pj.x, dy = pi.y - pj.y, dz = pi.z - pj.z;
        float r2 = fmaf(dx, dx, fmaf(dy, dy, dz * dz));
        bool m = (jj > jthresh) && (r2 > 0.f);
        float r2s = m ? r2 : 1e8f;
        float qq  = m ? qi * pj.w : 0.f;
        float t2  = __builtin_amdgcn_rsqf(r2s);            // 1/r
        float u   = fmaf(r2s * t2, 0.2f, -0.5f);           // (r-2.5)/5
        u = fminf(fmaxf(u, 1e-3f), 0.999f);                // exact 0/1 sat
        float d   = (u + u - 1.f) * __builtin_amdgcn_rcpf(fmaf(-u, u, u));
        float fs  = __builtin_amdgcn_rcpf(1.f + __expf(d));
        float t1  = __builtin_amdgcn_rsqf(r2s + 1.f);      // 1/sqrt(r2+1)
        acc = fmaf(qq, fmaf(fs, t1 - t2, t2), acc);
    }

    #pragma unroll
    for (int o2 = 32; o2 > 0; o2 >>= 1)
        acc += __shfl_down(acc, o2, 64);
    __syncthreads();                          // lred reuse
    if (lane == 0) lred[wid] = acc;
    __syncthreads();
    if (t == 0) {
        float be = lred[0] + lred[1] + lred[2] + lred[3];
        atomicAdd(&epart[b & 63], be);
    }

    // last-finishing-block energy finalize (wave 0)
    if (t < 64) {
        unsigned int old = 0;
        if (t == 0) {
            __threadfence();
            old = atomicAdd(counter, 1u);
        }
        old = __shfl(old, 0, 64);
        if (old == NREAL - 1) {
            float e = atomicAdd(&epart[t], 0.0f);   // coherent read
            #pragma unroll
            for (int o2 = 32; o2 > 0; o2 >>= 1)
                e += __shfl_down(e, o2, 64);
            if (t == 0) out0[0] = KE_KCAL * e;
        }
    }
}

extern "C" void kernel_launch(void* const* d_in, const int* in_sizes, int n_in,
                              void* d_out, int out_size, void* d_ws, size_t ws_size,
                              hipStream_t stream) {
    const float* f    = (const float*)d_in[0];
    const int*   z    = (const int*)  d_in[1];
    const float* xyz  = (const float*)d_in[2];
    const float* qtot = (const float*)d_in[3];
    const float* w    = (const float*)d_in[4];
    const float* ztab = (const float*)d_in[5];
    float* out = (float*)d_out;            // out[0]=energy, out[1..N]=q

    // ws: [0,256) epart[64] | [256] counter | [512, 512+1536) qpart[384]
    //     [16384, +98304) xqp[N] float4
    char* wsb = (char*)d_ws;
    float*        epart   = (float*)(wsb + 0);
    unsigned int* counter = (unsigned int*)(wsb + 256);
    float*        qpart   = (float*)(wsb + 512);
    float4*       xqp     = (float4*)(wsb + 16384);

    pred_kernel<<<NPRED, 256, 0, stream>>>(f, z, w, ztab, xyz,
                                           qpart, xqp, epart, counter);
    pair_kernel<<<NREAL, 256, 0, stream>>>(xqp, qpart, qtot, out + 1, epart,
                                           counter, out);
}

// Round 7
// 92.897 us; speedup vs baseline: 1.4641x; 1.0161x over previous
//
#include <hip/hip_runtime.h>

#define KE_KCAL 332.0637f

constexpr int N_ATOMS = 6144;
constexpr int NREAL = 1200;             // sum_{bi<24} (96 - 4*bi)
constexpr int NPRED = 384;              // pred blocks (16 atoms each)
constexpr int PAD = 32;                 // 32 words = 128 B, one L2 line/slot

// ---------------- kernel A: pred + per-block sums + pack + zero scratch -----
// 384 blocks x 256 threads, 4 atoms/wave. Block b plain-stores qpart[b].
// Block 0 zeroes epart/ctr1/ctr2 (visible to kernel B via stream order).
__global__ __launch_bounds__(256) void pred_kernel(
    const float* __restrict__ f, const int* __restrict__ z,
    const float* __restrict__ w, const float* __restrict__ ztab,
    const float* __restrict__ xyz,
    float* __restrict__ qpart, float4* __restrict__ xqp,
    float* __restrict__ epart, unsigned int* __restrict__ ctr1,
    unsigned int* __restrict__ ctr2)
{
    int t = threadIdx.x, b = blockIdx.x;
    int lane = t & 63, wid = t >> 6;

    if (b == 0) {
        if (t < 64) { epart[t * PAD] = 0.f; ctr1[t * PAD] = 0u; }
        if (t == 64) *ctr2 = 0u;
    }

    int base = b * 16 + wid * 4;
    const float2* f2 = (const float2*)f;
    float2 wv = ((const float2*)w)[lane];
    float2 v0 = f2[(size_t)(base + 0) * 64 + lane];
    float2 v1 = f2[(size_t)(base + 1) * 64 + lane];
    float2 v2 = f2[(size_t)(base + 2) * 64 + lane];
    float2 v3 = f2[(size_t)(base + 3) * 64 + lane];
    float p0 = fmaf(v0.x, wv.x, v0.y * wv.y);
    float p1 = fmaf(v1.x, wv.x, v1.y * wv.y);
    float p2 = fmaf(v2.x, wv.x, v2.y * wv.y);
    float p3 = fmaf(v3.x, wv.x, v3.y * wv.y);
    #pragma unroll
    for (int off = 32; off > 0; off >>= 1) {
        p0 += __shfl_xor(p0, off, 64);
        p1 += __shfl_xor(p1, off, 64);
        p2 += __shfl_xor(p2, off, 64);
        p3 += __shfl_xor(p3, off, 64);
    }
    float ws_sum = 0.f;
    if (lane < 4) {
        int atom = base + lane;
        float pk = p0;
        pk = (lane == 1) ? p1 : pk;
        pk = (lane == 2) ? p2 : pk;
        pk = (lane == 3) ? p3 : pk;
        pk += ztab[z[atom]];
        xqp[atom] = make_float4(xyz[3*atom], xyz[3*atom+1], xyz[3*atom+2], pk);
        ws_sum = pk;
    }
    ws_sum += __shfl_xor(ws_sum, 1, 64);
    ws_sum += __shfl_xor(ws_sum, 2, 64);

    __shared__ float lred[4];
    if (lane == 0) lred[wid] = ws_sum;
    __syncthreads();
    if (t == 0) qpart[b] = lred[0] + lred[1] + lred[2] + lred[3];
}

// ---------------- kernel B: pairwise energy, tree-counter finalize ----------
// 1200 triangular blocks x 256 threads. Block b -> (bi, bj), bj in [4*bi, 96).
// Branchless switch math (proven R4/R6). Completion detection is two-level:
// ctr1[b&63] (line-padded, ~19 deep each, parallel) -> ctr2 (64 deep) ->
// last block reduces the 64 line-padded epart slots. No 1200-deep serial tail.
__global__ __launch_bounds__(256) void pair_kernel(
    const float4* __restrict__ xqp, const float* __restrict__ qpart,
    const float* __restrict__ total_charge,
    float* __restrict__ qout, float* __restrict__ epart,
    unsigned int* __restrict__ ctr1, unsigned int* __restrict__ ctr2,
    float* __restrict__ out0)
{
    int t = threadIdx.x, b = blockIdx.x;
    int lane = t & 63, wid = t >> 6;
    __shared__ float lred[4];
    __shared__ float4 sj[64];

    // charge correction from the 384 per-block partials
    float s = qpart[t];
    if (t < NPRED - 256) s += qpart[256 + t];
    #pragma unroll
    for (int off = 32; off > 0; off >>= 1)
        s += __shfl_xor(s, off, 64);
    if (lane == 0) lred[wid] = s;
    __syncthreads();
    float S = lred[0] + lred[1] + lred[2] + lred[3];
    float corr = (total_charge[0] - S) * (1.0f / (float)N_ATOMS);

    // decode triangular (bi, bj)
    int bi = 0, off = 0;
    while (b >= off + (96 - 4 * bi)) { off += 96 - 4 * bi; ++bi; }
    int bj = 4 * bi + (b - off);

    int gj0 = bj * 64;
    if (t < 64) {
        float4 a = xqp[gj0 + t];
        a.w += corr;
        sj[t] = a;
    }
    int gi = bi * 256 + t;
    float4 pi = xqp[gi];
    float qi = pi.w + corr;
    if (bj == 4 * bi) qout[gi] = qi;
    __syncthreads();

    int jthresh = gi - gj0;                   // pair valid iff jj > jthresh
    float acc = 0.f;
    #pragma unroll 8
    for (int jj = 0; jj < 64; ++jj) {
        float4 pj = sj[jj];
        float dx = pi.x - pj.x, dy = pi.y - pj.y, dz = pi.z - pj.z;
        float r2 = fmaf(dx, dx, fmaf(dy, dy, dz * dz));
        bool m = (jj > jthresh) && (r2 > 0.f);
        float r2s = m ? r2 : 1e8f;
        float qq  = m ? qi * pj.w : 0.f;
        float t2  = __builtin_amdgcn_rsqf(r2s);            // 1/r
        float u   = fmaf(r2s * t2, 0.2f, -0.5f);           // (r-2.5)/5
        u = fminf(fmaxf(u, 1e-3f), 0.999f);                // exact 0/1 sat
        float d   = (u + u - 1.f) * __builtin_amdgcn_rcpf(fmaf(-u, u, u));
        float fs  = __builtin_amdgcn_rcpf(1.f + __expf(d));
        float t1  = __builtin_amdgcn_rsqf(r2s + 1.f);      // 1/sqrt(r2+1)
        acc = fmaf(qq, fmaf(fs, t1 - t2, t2), acc);
    }

    #pragma unroll
    for (int o2 = 32; o2 > 0; o2 >>= 1)
        acc += __shfl_down(acc, o2, 64);
    __syncthreads();                          // lred reuse
    if (lane == 0) lred[wid] = acc;
    __syncthreads();
    if (t == 0) {
        float be = lred[0] + lred[1] + lred[2] + lred[3];
        atomicAdd(&epart[(b & 63) * PAD], be);
    }

    // two-level completion + finalize (wave 0 only)
    if (t < 64) {
        bool last = false;
        if (t == 0) {
            int g = b & 63;
            unsigned int gcnt = (g < 48) ? 19u : 18u;   // 48*19 + 16*18 = 1200
            __threadfence();                  // epart add before ctr1
            unsigned int o1 = atomicAdd(&ctr1[g * PAD], 1u);
            if (o1 == gcnt - 1u) {
                __threadfence();
                unsigned int o2c = atomicAdd(ctr2, 1u);
                last = (o2c == 63u);
            }
        }
        last = (bool)__shfl((int)last, 0, 64);
        if (last) {
            float e = atomicAdd(&epart[t * PAD], 0.0f);   // coherent read
            #pragma unroll
            for (int o2 = 32; o2 > 0; o2 >>= 1)
                e += __shfl_down(e, o2, 64);
            if (t == 0) out0[0] = KE_KCAL * e;
        }
    }
}

extern "C" void kernel_launch(void* const* d_in, const int* in_sizes, int n_in,
                              void* d_out, int out_size, void* d_ws, size_t ws_size,
                              hipStream_t stream) {
    const float* f    = (const float*)d_in[0];
    const int*   z    = (const int*)  d_in[1];
    const float* xyz  = (const float*)d_in[2];
    const float* qtot = (const float*)d_in[3];
    const float* w    = (const float*)d_in[4];
    const float* ztab = (const float*)d_in[5];
    float* out = (float*)d_out;            // out[0]=energy, out[1..N]=q

    // ws: [0, 8192)      epart[64] line-padded
    //     [8192, 16384)  ctr1[64]  line-padded
    //     [16384]        ctr2
    //     [16896, +1536) qpart[384]
    //     [32768, +98304) xqp[N] float4
    char* wsb = (char*)d_ws;
    float*        epart = (float*)(wsb + 0);
    unsigned int* ctr1  = (unsigned int*)(wsb + 8192);
    unsigned int* ctr2  = (unsigned int*)(wsb + 16384);
    float*        qpart = (float*)(wsb + 16896);
    float4*       xqp   = (float4*)(wsb + 32768);

    pred_kernel<<<NPRED, 256, 0, stream>>>(f, z, w, ztab, xyz,
                                           qpart, xqp, epart, ctr1, ctr2);
    pair_kernel<<<NREAL, 256, 0, stream>>>(xqp, qpart, qtot, out + 1, epart,
                                           ctr1, ctr2, out);
}